// Round 1
// baseline (15.648 us; speedup 1.0000x reference)
//
#include <hip/hip_runtime.h>
#include <hip/hip_bf16.h>

// Closed-form of the 2-qubit circuit:
//   out0 = 0.5*(1 + cos(ry)*cos(x0) - sin(ry)*cos(rz)*sin(x0)*sin(x1))
//   out1 = 0.5*(1 + cos(ry)*cos(x1))
// Derivation: amplitudes after the circuit have the form a*e^{-i t} + b*e^{+i t}
// (t = rz/2, a,b real), so |.|^2 = a^2 + b^2 + 2ab*cos(rz); summing the four
// probabilities with half-angle identities collapses everything above.

__global__ void __launch_bounds__(256)
qc2_expval_kernel(const float4* __restrict__ x4,
                  const float* __restrict__ theta_rz,
                  const float* __restrict__ theta_ry,
                  float4* __restrict__ out4,
                  int n4) {
    int i = blockIdx.x * blockDim.x + threadIdx.x;
    if (i >= n4) return;

    // Scalar params (broadcast loads, L1-resident). 3 transcendentals/thread.
    float ry = theta_ry[0];
    float rz = theta_rz[0];
    float cry = __cosf(ry);
    float srycrz = __sinf(ry) * __cosf(rz);

    float4 v = x4[i];  // two rows: (x0,x1) = (v.x,v.y) and (v.z,v.w)

    float s0a, c0a, s1a, c1a;
    __sincosf(v.x, &s0a, &c0a);
    __sincosf(v.y, &s1a, &c1a);

    float s0b, c0b, s1b, c1b;
    __sincosf(v.z, &s0b, &c0b);
    __sincosf(v.w, &s1b, &c1b);

    float4 o;
    o.x = 0.5f * (1.0f + cry * c0a - srycrz * s0a * s1a);
    o.y = 0.5f * (1.0f + cry * c1a);
    o.z = 0.5f * (1.0f + cry * c0b - srycrz * s0b * s1b);
    o.w = 0.5f * (1.0f + cry * c1b);
    out4[i] = o;
}

extern "C" void kernel_launch(void* const* d_in, const int* in_sizes, int n_in,
                              void* d_out, int out_size, void* d_ws, size_t ws_size,
                              hipStream_t stream) {
    const float4* x4       = (const float4*)d_in[0];       // [B,2] f32 -> B/2 float4
    const float*  theta_rz = (const float*)d_in[1];
    const float*  theta_ry = (const float*)d_in[2];
    float4* out4 = (float4*)d_out;                         // [B,2] f32 -> B/2 float4

    int total_f = out_size;          // B*2 floats
    int n4 = total_f / 4;            // B*2 divisible by 4 (B = 4194304)

    int block = 256;
    int grid = (n4 + block - 1) / block;
    qc2_expval_kernel<<<grid, block, 0, stream>>>(x4, theta_rz, theta_ry, out4, n4);
}

// Round 2
// 13.667 us; speedup vs baseline: 1.1450x; 1.1450x over previous
//
#include <hip/hip_runtime.h>
#include <hip/hip_bf16.h>

// Closed-form of the 2-qubit circuit:
//   out0 = 0.5*(1 + cos(ry)*cos(x0) - sin(ry)*cos(rz)*sin(x0)*sin(x1))
//   out1 = 0.5*(1 + cos(ry)*cos(x1))
// (amplitudes are a*e^{-i rz/2} + b*e^{+i rz/2} with a,b real ->
//  |.|^2 = a^2+b^2+2ab*cos(rz); half-angle identities collapse the rest)

typedef float f32x4 __attribute__((ext_vector_type(4)));

__global__ void __launch_bounds__(256)
qc2_expval_kernel(const f32x4* __restrict__ x4,
                  const float* __restrict__ theta_rz,
                  const float* __restrict__ theta_ry,
                  f32x4* __restrict__ out4,
                  int n4) {
    // Block-uniform scalar params; 3 transcendentals/thread, hoisted.
    float ry = theta_ry[0];
    float cry = __cosf(ry);
    float srycrz = __sinf(ry) * __cosf(theta_rz[0]);

    int base   = blockIdx.x * blockDim.x + threadIdx.x;
    int stride = gridDim.x * blockDim.x;

    // 4 strided float4s per thread: issue loads first (ILP), then compute.
    f32x4 v[4];
    int idx[4];
    bool ok[4];
#pragma unroll
    for (int k = 0; k < 4; ++k) {
        idx[k] = base + k * stride;
        ok[k]  = idx[k] < n4;
        if (ok[k]) v[k] = x4[idx[k]];
    }

#pragma unroll
    for (int k = 0; k < 4; ++k) {
        if (!ok[k]) continue;
        float s0a, c0a, s1a, c1a, s0b, c0b, s1b, c1b;
        __sincosf(v[k].x, &s0a, &c0a);
        __sincosf(v[k].y, &s1a, &c1a);
        __sincosf(v[k].z, &s0b, &c0b);
        __sincosf(v[k].w, &s1b, &c1b);
        f32x4 o;
        o.x = 0.5f * (1.0f + cry * c0a - srycrz * s0a * s1a);
        o.y = 0.5f * (1.0f + cry * c1a);
        o.z = 0.5f * (1.0f + cry * c0b - srycrz * s0b * s1b);
        o.w = 0.5f * (1.0f + cry * c1b);
        // Output is write-only during timed replays: non-temporal store keeps
        // L2/L3 clean so the (L3-resident) input stream stays hot.
        __builtin_nontemporal_store(o, &out4[idx[k]]);
    }
}

extern "C" void kernel_launch(void* const* d_in, const int* in_sizes, int n_in,
                              void* d_out, int out_size, void* d_ws, size_t ws_size,
                              hipStream_t stream) {
    const f32x4* x4       = (const f32x4*)d_in[0];   // [B,2] f32 -> B/2 float4
    const float* theta_rz = (const float*)d_in[1];
    const float* theta_ry = (const float*)d_in[2];
    f32x4* out4 = (f32x4*)d_out;

    int total_f = out_size;   // B*2 floats
    int n4 = total_f / 4;     // 2,097,152 for B = 4,194,304

    int block = 256;
    int max_blocks = 2048;    // 256 CU x 8 blocks/CU; grid-stride the rest
    int grid = (n4 + block - 1) / block;
    if (grid > max_blocks) grid = max_blocks;
    qc2_expval_kernel<<<grid, block, 0, stream>>>(x4, theta_rz, theta_ry, out4, n4);
}